// Round 10
// baseline (340.887 us; speedup 1.0000x reference)
//
#include <hip/hip_runtime.h>
#include <hip/hip_cooperative_groups.h>
#include <stdint.h>

namespace cg = cooperative_groups;

typedef float f4 __attribute__((ext_vector_type(4)));
typedef float f32x4 __attribute__((ext_vector_type(4)));
typedef _Float16 hq4 __attribute__((ext_vector_type(4)));
typedef _Float16 half8 __attribute__((ext_vector_type(8)));

#define DF 128    // input feature dim
#define HID 64    // hidden dim
#define EPB 4096  // edges per sort unit (391 units; R17: long write runs win)
#define CAP 5120  // slots per coarse bucket (avg 4096, max~4314 seed-0)
#define SMEM_BYTES 55360   // P1 sort union; 2 blocks/CU (110.7KB of 160KB)

// ---------- R26: single cooperative mega-kernel ----------
// R9 accounting: kernel time ~125us vs 193us total -> ~68us is inter-dispatch
// overhead across 5 dispatches. All phases fused with grid.sync() between.
// Phase math is bit-identical to R9 (absmax must stay 0.001953125).
//   P0: zero cur                         (replaces hipMemsetAsync)
//   P1: coarse sort || gemm h=fp16(x@W1) (R9 kFusedA verbatim, guards not returns)
//   P2: fine sort per bucket             (R9 kB, se-staging dropped: tmp re-read
//                                         from L2; LDS 3KB so union stays 55.3KB)
//   P3: agg+relu+@W2, 8 waves x 4 nodes  (R9 k_agg_h2, dinv applied at staging)
//   P4: layer-2 out                      (R9 k_out)
__global__ __launch_bounds__(512) void kMega(
    const int* __restrict__ row, const int* __restrict__ col,
    const float* __restrict__ ew, const float* __restrict__ x,
    const float* __restrict__ W1, const float* __restrict__ b1,
    const float* __restrict__ W2, const float* __restrict__ b2,
    float* __restrict__ out,
    int* __restrict__ cur, int2* __restrict__ tmp, int2* __restrict__ edata,
    int2* __restrict__ offse, float* __restrict__ dinv,
    _Float16* __restrict__ h, float* __restrict__ h2p,
    int E, int N, int nblk, int nbin, int nstrip, int gemmB)
{
    __shared__ __align__(16) char smem[SMEM_BYTES];
    cg::grid_group grid = cg::this_grid();
    int t = threadIdx.x;
    int nb = gridDim.x;

    // ================= P0: zero bucket counters =================
    for (int i = blockIdx.x * 512 + t; i < nbin; i += nb * 512) cur[i] = 0;
    grid.sync();

    // ================= P1: coarse sort || gemm =================
    {
        int p1u = nblk + gemmB;
        for (int u = blockIdx.x; u < p1u; u += nb) {
            __syncthreads();   // protect smem union across units/branches
            if (u < nblk) {
                // ---- sort unit (R3/R5/R9-proven dataflow) ----
                int*  hist  = (int*)smem;                    // 2048B
                int*  pref  = hist + 512;                    // 2048B
                int*  lbase = pref + 512;                    // 2048B
                int*  wsum  = lbase + 512;                   // 32B
                int2* sv    = (int2*)(smem + 6208);          // 32KB
                int*  sa    = (int*)(smem + 6208 + 32768);   // 16KB
                hist[t] = 0;
                __syncthreads();
                int s = u * EPB, e = min(E, s + EPB);
                int cnt = e - s;
                int  mybin[8], myrank[8];
                int2 myv[8];
#pragma unroll
                for (int k = 0; k < 8; ++k) {
                    int i = s + t + k * 512;
                    mybin[k] = -1;
                    if (i < e) {
                        int c = col[i];
                        int bin = c >> 8;
                        myv[k].x = row[i] | ((c & 255) << 24);  // src|fine<<24
                        myv[k].y = __float_as_int(ew[i]);
                        mybin[k] = bin;
                        myrank[k] = atomicAdd(&hist[bin], 1);
                    }
                }
                __syncthreads();
                int val = hist[t];
                lbase[t] = val ? atomicAdd(&cur[t], val) + t * CAP : 0;
                int lane = t & 63, wid = t >> 6;
                int inc = val;
#pragma unroll
                for (int d = 1; d < 64; d <<= 1) {
                    int y = __shfl_up(inc, d);
                    if (lane >= d) inc += y;
                }
                if (lane == 63) wsum[wid] = inc;
                __syncthreads();
                if (t == 0) {
                    int r = 0;
#pragma unroll
                    for (int i = 0; i < 8; ++i) { int xx = wsum[i]; wsum[i] = r; r += xx; }
                }
                __syncthreads();
                pref[t] = inc - val + wsum[wid];   // excl prefix within unit
                __syncthreads();
#pragma unroll
                for (int k = 0; k < 8; ++k) {
                    if (mybin[k] >= 0) {
                        int pos = pref[mybin[k]] + myrank[k];
                        sv[pos] = myv[k];
                        sa[pos] = lbase[mybin[k]] + myrank[k];
                    }
                }
                __syncthreads();
                for (int i = t; i < cnt; i += 512) tmp[sa[i]] = sv[i];
            } else {
                // ---- gemm unit: h = fp16(x @ W1), UNSCALED ----
                _Float16* W1f = (_Float16*)smem;             // 16KB fragments
                for (int i = t; i < 8192; i += 512) {
                    int j     = i & 7;
                    int lane  = (i >> 3) & 63;
                    int ntile = (i >> 9) & 3;
                    int kstep = i >> 11;
                    int k = kstep * 32 + (lane >> 4) * 8 + j;
                    int n = ntile * 16 + (lane & 15);
                    W1f[i] = (_Float16)W1[k * 64 + n];       // L2-hot
                }
                __syncthreads();
                int wave = (u - nblk) * 8 + (t >> 6);
                if (wave < nstrip) {                          // guard, no return
                    int node0 = wave << 4;
                    int l = t & 63;
                    int quad = l >> 4;
                    int m = l & 15;
                    int r = node0 + m;
                    if (r >= N) r = N - 1;   // clamp (harmless dup load)
                    const half8* bfrag = (const half8*)W1f;
                    f32x4 acc[4];
#pragma unroll
                    for (int nt = 0; nt < 4; ++nt) acc[nt] = (f32x4)(0.f);
#pragma unroll
                    for (int kstep = 0; kstep < 4; ++kstep) {
                        const f4* xr = (const f4*)(x + (size_t)r * DF + kstep * 32 + quad * 8);
                        f4 a0 = xr[0], a1 = xr[1];
                        half8 af;
                        af[0] = (_Float16)a0.x; af[1] = (_Float16)a0.y;
                        af[2] = (_Float16)a0.z; af[3] = (_Float16)a0.w;
                        af[4] = (_Float16)a1.x; af[5] = (_Float16)a1.y;
                        af[6] = (_Float16)a1.z; af[7] = (_Float16)a1.w;
#pragma unroll
                        for (int nt = 0; nt < 4; ++nt) {
                            half8 bf = bfrag[(kstep * 4 + nt) * 64 + l];
                            acc[nt] = __builtin_amdgcn_mfma_f32_16x16x32_f16(af, bf, acc[nt], 0, 0, 0);
                        }
                    }
                    int nodeb = node0 + quad * 4;
#pragma unroll
                    for (int nt = 0; nt < 4; ++nt) {
#pragma unroll
                        for (int reg = 0; reg < 4; ++reg) {
                            int node = nodeb + reg;
                            if (node < N)
                                h[(unsigned)node * 64u + (unsigned)(nt * 16 + m)] =
                                    (_Float16)acc[nt][reg];
                        }
                    }
                }
            }
        }
    }
    grid.sync();

    // ================= P2: fine sort per bucket (no se staging) =================
    {
        int*   hist = (int*)smem;            // 1KB
        float* degl = (float*)(smem + 1024); // 1KB
        int*   fill = (int*)(smem + 2048);   // 1KB
        int*   wsum = (int*)(smem + 3072);   // 32B
        for (int u = blockIdx.x; u < nbin; u += nb) {
            int s = u * CAP;
            int cnt = min(cur[u], CAP);
            if (t < 256) { hist[t] = 0; degl[t] = 0.f; }
            __syncthreads();
            for (int i = t; i < cnt; i += 512) {
                int2 pr = tmp[s + i];
                int lo = ((unsigned)pr.x) >> 24;
                atomicAdd(&hist[lo], 1);
                atomicAdd(&degl[lo], __int_as_float(pr.y));
            }
            __syncthreads();
            int val = (t < 256) ? hist[t] : 0;
            int lane = t & 63, wid = t >> 6;
            int inc = val;
#pragma unroll
            for (int d = 1; d < 64; d <<= 1) {
                int y = __shfl_up(inc, d);
                if (lane >= d) inc += y;
            }
            if (lane == 63) wsum[wid] = inc;
            __syncthreads();
            if (t == 0) {
                int r = 0;
#pragma unroll
                for (int i = 0; i < 8; ++i) { int xx = wsum[i]; wsum[i] = r; r += xx; }
            }
            __syncthreads();
            int pfx = inc - val + wsum[wid];   // excl prefix (valid t<256)
            if (t < 256) {
                fill[t] = pfx;
                int c = u * 256 + t;
                if (c < N) {
                    int2 oe;
                    oe.x = s + pfx;
                    oe.y = s + pfx + val;
                    offse[c] = oe;
                    dinv[c] = rsqrtf(1.0f + degl[t]);   // deg >= 1 (self-loop)
                }
            }
            __syncthreads();
            for (int i = t; i < cnt; i += 512) {
                int2 pr = tmp[s + i];               // re-read: L2-hot 40KB window
                int lo = ((unsigned)pr.x) >> 24;
                int pos = atomicAdd(&fill[lo], 1);
                int2 o;
                o.x = pr.x & 0x00FFFFFF;
                o.y = pr.y;
                edata[s + pos] = o;                 // scatter in 40KB window
            }
            __syncthreads();   // protect hist/fill reuse across units
        }
    }
    grid.sync();

    // ================= P3: layer-1 agg + relu + @W2 (8 waves x 4 nodes) ========
    {
        int2 (*stage)[68] = (int2(*)[68])smem;   // 8 x (4 groups x 17) = 4352B
        int wv = t >> 6;
        int l  = t & 63;
        int g  = l >> 4;
        unsigned fq = (unsigned)(l & 15);
        int sbase = g * 17;
        const hq4* hp = (const hq4*)h;
        int p3u = (N + 31) >> 5;
        for (int u = blockIdx.x; u < p3u; u += nb) {
            int vv = u * 32 + wv * 4 + g;
            bool ok = vv < N;
            int v = ok ? vv : N - 1;
            float di = dinv[v];
            int2 oe = offse[v];
            hq4 sv4 = hp[((unsigned)v << 4) | fq];
            float a0 = di * (float)sv4.x, a1 = di * (float)sv4.y;
            float a2 = di * (float)sv4.z, a3 = di * (float)sv4.w;
            int deg = oe.y - oe.x;
            for (int base = 0; base < deg; base += 16) {
                int idx = oe.x + base + (int)fq;
                int2 pr;
                pr.x = 0; pr.y = 0;
                if (idx < oe.y) {
                    pr = edata[idx];
                    pr.y = __float_as_int(__int_as_float(pr.y) * dinv[pr.x]); // ws once/edge
                }
                stage[wv][sbase + (int)fq] = pr;   // wave-private row
#pragma unroll
                for (int k = 0; k < 16; ++k) {
                    int2 em = stage[wv][sbase + k];
                    float ws = __int_as_float(em.y);
                    hq4 hv = hp[((unsigned)em.x << 4) | fq];
                    a0 += ws * (float)hv.x;
                    a1 += ws * (float)hv.y;
                    a2 += ws * (float)hv.z;
                    a3 += ws * (float)hv.w;
                }
            }
            a0 = di * a0; a1 = di * a1; a2 = di * a2; a3 = di * a3;
            f4 bb = ((const f4*)b1)[fq];
            f4 ww = ((const f4*)W2)[fq];
            float s2 = fmaxf(a0 + bb.x, 0.f) * ww.x
                     + fmaxf(a1 + bb.y, 0.f) * ww.y
                     + fmaxf(a2 + bb.z, 0.f) * ww.z
                     + fmaxf(a3 + bb.w, 0.f) * ww.w;
            s2 += __shfl_down(s2, 8);
            s2 += __shfl_down(s2, 4);
            s2 += __shfl_down(s2, 2);
            s2 += __shfl_down(s2, 1);
            if (fq == 0 && ok) h2p[vv] = di * s2;
        }
    }
    grid.sync();

    // ================= P4: layer-2 out (16 lanes/node) =================
    {
        int p4u = (N + 31) >> 5;   // 32 nodes per 512-thread unit
        for (int u = blockIdx.x; u < p4u; u += nb) {
            int tt = u * 512 + t;
            int v = tt >> 4;
            if (v < N) {
                int c = tt & 15;
                int2 oe = offse[v];
                float s2 = 0.f;
                for (int i = oe.x + c; i < oe.y; i += 16) {
                    int2 pr = edata[i];
                    s2 += __int_as_float(pr.y) * h2p[(unsigned)pr.x];
                }
                s2 += __shfl_down(s2, 8);
                s2 += __shfl_down(s2, 4);
                s2 += __shfl_down(s2, 2);
                s2 += __shfl_down(s2, 1);
                if (c == 0) {
                    float di = dinv[v];
                    out[v] = b2[0] + di * (h2p[v] + s2);   // h2p[v] = di*h2[v]
                }
            }
        }
    }
}

extern "C" void kernel_launch(void* const* d_in, const int* in_sizes, int n_in,
                              void* d_out, int out_size, void* d_ws, size_t ws_size,
                              hipStream_t stream) {
    const float* x  = (const float*)d_in[0];
    const int*   ei = (const int*)d_in[1];
    const float* ew = (const float*)d_in[2];
    const float* W1 = (const float*)d_in[3];
    const float* b1 = (const float*)d_in[4];
    const float* W2 = (const float*)d_in[5];
    const float* b2 = (const float*)d_in[6];
    float* out = (float*)d_out;

    const int N = in_sizes[0] / DF;       // 100000
    const int E = in_sizes[2];            // 1600000
    const int* row = ei;                  // sources
    const int* col = ei + E;              // targets

    const int nbin = (N + 255) / 256;     // 391 coarse buckets
    const int nblk = (E + EPB - 1) / EPB; // 391 sort units

    // ---- workspace layout, ~46.5 MB (same as R9) ----
    size_t    gsz   = (size_t)nbin * CAP;
    int2*     edata = (int2*)d_ws;                        // 16.0 MB
    int2*     tmp   = edata + gsz;                        // 16.0 MB
    _Float16* h     = (_Float16*)(tmp + gsz);             // 12.8 MB
    int       nbinPad = (nbin + 3) & ~3;
    int*      cur   = (int*)(h + (size_t)N * 64);         // nbinPad ints
    float*    dinv  = (float*)(cur + nbinPad);            // N floats
    float*    h2p   = dinv + N;                           // N floats
    int2*     offse = (int2*)(h2p + N);                   // N int2

    int nstrip = (N + 15) / 16;            // 6250 GEMM strips
    int gemmB  = (nstrip + 7) / 8;         // 782 gemm units

    // cooperative grid = maxActiveBlocks x CU count (runtime-validated)
    static int nbCached = 0;
    if (nbCached == 0) {
        int dev = 0;
        hipGetDevice(&dev);
        hipDeviceProp_t prop;
        hipGetDeviceProperties(&prop, dev);
        int maxB = 0;
        hipOccupancyMaxActiveBlocksPerMultiprocessor(&maxB, (const void*)kMega, 512, 0);
        if (maxB < 1) maxB = 1;
        nbCached = maxB * prop.multiProcessorCount;   // expect 2 x 256 = 512
        if (nbCached < 1) nbCached = 256;
    }
    int nb = nbCached;

    void* args[] = {
        (void*)&row, (void*)&col, (void*)&ew, (void*)&x, (void*)&W1,
        (void*)&b1, (void*)&W2, (void*)&b2, (void*)&out,
        (void*)&cur, (void*)&tmp, (void*)&edata, (void*)&offse, (void*)&dinv,
        (void*)&h, (void*)&h2p,
        (void*)&E, (void*)&N, (void*)&nblk, (void*)&nbin,
        (void*)&nstrip, (void*)&gemmB
    };
    hipLaunchCooperativeKernel((void*)kMega, dim3(nb), dim3(512), args, 0, stream);
}